// Round 5
// baseline (616.470 us; speedup 1.0000x reference)
//
#include <hip/hip_runtime.h>
#include <hip/hip_bf16.h>
#include <math.h>

// B=2,H=16 (BH=32), T=2048, D=64. fp32 in/out.
// d_out = [out (BH*T*64) | attn (BH*T*T)] fp32.
//
// R5: barrier-free two-pass chunked attention.
//  - wave owns 16 q-rows x all 2048 cols; block = 4 independent waves.
//  - pass A: hi*hi QK^T -> exp -> rowsum only (P discarded; rel err ~5e-4).
//  - pass B: per 128-col chunk: compensated QK^T -> exp*inv (normalized P)
//    -> LDS roundtrip -> PV MFMA -> f32x4 nt attn stores (overlapped).
//  - no __syncthreads anywhere; out = wave-local PV accs, stored directly.
//  - launch_bounds(256,3): <=170 VGPR, 12 waves/CU (vs 8 in R3/R4).

#define T_SEQ  2048
#define D_HEAD 64
#define BH_N   32
#define CHK    16            // chunks per row
#define OUT_ELEMS (BH_N * T_SEQ * D_HEAD)

typedef __attribute__((ext_vector_type(8))) short bf16x8;
typedef __attribute__((ext_vector_type(4))) float f32x4;

__device__ __forceinline__ unsigned short f2bf(float x) {
    __hip_bfloat16 h = __float2bfloat16(x);
    return *reinterpret_cast<unsigned short*>(&h);
}
__device__ __forceinline__ float bf2f(unsigned short u) {
    __hip_bfloat16 h;
    *reinterpret_cast<unsigned short*>(&h) = u;
    return __bfloat162float(h);
}

// ---------------- precompute: rope tables ----------------
__global__ void rope_table_kernel(float* __restrict__ ctab, float* __restrict__ stab) {
    int i = blockIdx.x * blockDim.x + threadIdx.x;
    if (i >= T_SEQ * 32) return;
    int t = i >> 5;
    int j = i & 31;
    float invf = powf(10000.0f, -(float)j / 32.0f);
    float a = (float)t * invf;
    ctab[i] = cosf(a);
    stab[i] = sinf(a);
}

// ---------------- precompute: rope + hi/lo split for Q,K ----------------
__global__ __launch_bounds__(256)
void ropesplit_kernel(const float* __restrict__ X, const float* __restrict__ ctab,
                      const float* __restrict__ stab, unsigned short* __restrict__ H,
                      unsigned short* __restrict__ L, float scale)
{
    const int r  = blockIdx.x * 16 + (threadIdx.x >> 4);   // global row in [0, BH*T)
    const int c4 = threadIdx.x & 15;
    const int t  = r & (T_SEQ - 1);
    const float4* xr = (const float4*)(X + (size_t)r * 64);
    float4 a = xr[c4];
    float4 b = xr[c4 ^ 8];
    float4 c = ((const float4*)(ctab + t * 32))[c4 & 7];
    float4 s = ((const float4*)(stab + t * 32))[c4 & 7];
    float4 ro;
    if (c4 < 8) {
        ro.x = a.x * c.x - b.x * s.x; ro.y = a.y * c.y - b.y * s.y;
        ro.z = a.z * c.z - b.z * s.z; ro.w = a.w * c.w - b.w * s.w;
    } else {
        ro.x = a.x * c.x + b.x * s.x; ro.y = a.y * c.y + b.y * s.y;
        ro.z = a.z * c.z + b.z * s.z; ro.w = a.w * c.w + b.w * s.w;
    }
    ro.x *= scale; ro.y *= scale; ro.z *= scale; ro.w *= scale;
    ushort4 h, l;
    h.x = f2bf(ro.x); l.x = f2bf(ro.x - bf2f(h.x));
    h.y = f2bf(ro.y); l.y = f2bf(ro.y - bf2f(h.y));
    h.z = f2bf(ro.z); l.z = f2bf(ro.z - bf2f(h.z));
    h.w = f2bf(ro.w); l.w = f2bf(ro.w - bf2f(h.w));
    *(ushort4*)(H + (size_t)r * 64 + c4 * 4) = h;
    *(ushort4*)(L + (size_t)r * 64 + c4 * 4) = l;
}

// ---------------- precompute: V transpose + hi/lo split ----------------
__global__ __launch_bounds__(256)
void vtrans_kernel(const float* __restrict__ V, unsigned short* __restrict__ Vth,
                   unsigned short* __restrict__ Vtl)
{
    __shared__ float tile[64][65];
    const int bh = blockIdx.y;
    const int tt = blockIdx.x;            // 64-row t-tile
    const float* vg = V + ((size_t)bh * T_SEQ + tt * 64) * 64;
    #pragma unroll
    for (int i = 0; i < 4; ++i) {
        const int row = (threadIdx.x >> 4) + i * 16;
        const int c4  = threadIdx.x & 15;
        float4 a = *(const float4*)(vg + (size_t)row * 64 + c4 * 4);
        tile[row][c4 * 4 + 0] = a.x; tile[row][c4 * 4 + 1] = a.y;
        tile[row][c4 * 4 + 2] = a.z; tile[row][c4 * 4 + 3] = a.w;
    }
    __syncthreads();
    #pragma unroll
    for (int i = 0; i < 4; ++i) {
        const int d   = (threadIdx.x >> 4) + i * 16;
        const int tc4 = threadIdx.x & 15;
        ushort4 h, l;
        float x0 = tile[tc4 * 4 + 0][d];
        float x1 = tile[tc4 * 4 + 1][d];
        float x2 = tile[tc4 * 4 + 2][d];
        float x3 = tile[tc4 * 4 + 3][d];
        h.x = f2bf(x0); l.x = f2bf(x0 - bf2f(h.x));
        h.y = f2bf(x1); l.y = f2bf(x1 - bf2f(h.y));
        h.z = f2bf(x2); l.z = f2bf(x2 - bf2f(h.z));
        h.w = f2bf(x3); l.w = f2bf(x3 - bf2f(h.w));
        size_t off = ((size_t)bh * 64 + d) * T_SEQ + tt * 64 + tc4 * 4;
        *(ushort4*)(Vth + off) = h;
        *(ushort4*)(Vtl + off) = l;
    }
}

// ---------------- main attention kernel ----------------
__global__ __launch_bounds__(256, 3)
void attn_mfma_kernel(const unsigned short* __restrict__ Qh, const unsigned short* __restrict__ Ql,
                      const unsigned short* __restrict__ Kh, const unsigned short* __restrict__ Kl,
                      const unsigned short* __restrict__ Vth, const unsigned short* __restrict__ Vtl,
                      float* __restrict__ out, float* __restrict__ attn)
{
    // per-wave P staging: 16 rows x 128 cols bf16, stride 136 shorts (272 B, 16B-aligned rows)
    __shared__ __align__(16) unsigned short pbuf[4][16][136];   // 17408 B

    const int tid  = threadIdx.x;
    const int lane = tid & 63;
    const int w    = tid >> 6;
    const int lrow = lane & 15;     // q-row within wave / A-row / B-col
    const int lgrp = lane >> 4;

    // XCD-aware bijective swizzle: 1024 blocks = 8 * 128
    const int lid = blockIdx.x;
    const int vid = (lid & 7) * 128 + (lid >> 3);
    const int bh  = vid >> 5;
    const int m   = vid & 31;
    const int t0  = m * 64 + w * 16;   // this wave's first q-row

    const size_t base = (size_t)bh * T_SEQ * D_HEAD;
    const unsigned short* qh  = Qh  + base;
    const unsigned short* ql  = Ql  + base;
    const unsigned short* kh  = Kh  + base;
    const unsigned short* kl  = Kl  + base;
    const unsigned short* vth = Vth + base;   // layout [bh][64][T]
    const unsigned short* vtl = Vtl + base;

    // --- Q fragments as B-operand: col = lrow = q-row, k-slice = lgrp*8 ---
    bf16x8 qfh[2], qfl[2];
    #pragma unroll
    for (int ks = 0; ks < 2; ++ks) {
        const int off = (t0 + lrow) * 64 + ks * 32 + lgrp * 8;
        qfh[ks] = *(const bf16x8*)(qh + off);
        qfl[ks] = *(const bf16x8*)(ql + off);
    }

    // ---------------- pass A: rowsum (hi*hi only) ----------------
    float rp = 0.f;
    for (int cc = 0; cc < CHK; ++cc) {
        f32x4 s[8];
        #pragma unroll
        for (int n8 = 0; n8 < 8; ++n8) s[n8] = (f32x4){0.f, 0.f, 0.f, 0.f};
        #pragma unroll
        for (int n8 = 0; n8 < 8; ++n8) {
            const int coff = ((cc * 8 + n8) * 16 + lrow) * 64 + lgrp * 8;
            bf16x8 k_h0 = *(const bf16x8*)(kh + coff);
            bf16x8 k_h1 = *(const bf16x8*)(kh + coff + 32);
            s[n8] = __builtin_amdgcn_mfma_f32_16x16x32_bf16(k_h0, qfh[0], s[n8], 0, 0, 0);
            s[n8] = __builtin_amdgcn_mfma_f32_16x16x32_bf16(k_h1, qfh[1], s[n8], 0, 0, 0);
        }
        #pragma unroll
        for (int n8 = 0; n8 < 8; ++n8)
            #pragma unroll
            for (int j = 0; j < 4; ++j)
                rp += __expf(s[n8][j]);
    }
    rp += __shfl_xor(rp, 16, 64);
    rp += __shfl_xor(rp, 32, 64);        // all lanes: full rowsum for q = lrow
    const float inv = 1.0f / rp;

    // ---------------- pass B: attn + PV (normalized P) ----------------
    f32x4 o[4];
    #pragma unroll
    for (int nd = 0; nd < 4; ++nd) o[nd] = (f32x4){0.f, 0.f, 0.f, 0.f};

    float* arow = attn + (size_t)bh * T_SEQ * T_SEQ + (size_t)(t0 + lrow) * T_SEQ + lgrp * 4;
    unsigned short* pb = &pbuf[w][0][0];

    for (int cc = 0; cc < CHK; ++cc) {
        f32x4 s[8];
        #pragma unroll
        for (int n8 = 0; n8 < 8; ++n8) s[n8] = (f32x4){0.f, 0.f, 0.f, 0.f};
        #pragma unroll
        for (int n8 = 0; n8 < 8; ++n8) {
            const int coff = ((cc * 8 + n8) * 16 + lrow) * 64 + lgrp * 8;
            bf16x8 k_h0 = *(const bf16x8*)(kh + coff);
            bf16x8 k_h1 = *(const bf16x8*)(kh + coff + 32);
            bf16x8 k_l0 = *(const bf16x8*)(kl + coff);
            bf16x8 k_l1 = *(const bf16x8*)(kl + coff + 32);
            f32x4 acc = s[n8];
            acc = __builtin_amdgcn_mfma_f32_16x16x32_bf16(k_h0, qfh[0], acc, 0, 0, 0);
            acc = __builtin_amdgcn_mfma_f32_16x16x32_bf16(k_h1, qfh[1], acc, 0, 0, 0);
            acc = __builtin_amdgcn_mfma_f32_16x16x32_bf16(k_h0, qfl[0], acc, 0, 0, 0);
            acc = __builtin_amdgcn_mfma_f32_16x16x32_bf16(k_h1, qfl[1], acc, 0, 0, 0);
            acc = __builtin_amdgcn_mfma_f32_16x16x32_bf16(k_l0, qfh[0], acc, 0, 0, 0);
            acc = __builtin_amdgcn_mfma_f32_16x16x32_bf16(k_l1, qfh[1], acc, 0, 0, 0);
            s[n8] = acc;
        }
        // exp * inv -> normalized P; stage bf16 into LDS
        #pragma unroll
        for (int n8 = 0; n8 < 8; ++n8) {
            f32x4 p;
            p.x = __expf(s[n8][0]) * inv;
            p.y = __expf(s[n8][1]) * inv;
            p.z = __expf(s[n8][2]) * inv;
            p.w = __expf(s[n8][3]) * inv;
            s[n8] = p;
            ushort4 p4;
            p4.x = f2bf(p.x); p4.y = f2bf(p.y); p4.z = f2bf(p.z); p4.w = f2bf(p.w);
            *(ushort4*)(pb + lrow * 136 + n8 * 16 + lgrp * 4) = p4;
        }
        asm volatile("s_waitcnt lgkmcnt(0)" ::: "memory");
        __builtin_amdgcn_sched_barrier(0);
        // PV: o += P(16q x 128s) * V(128s x 64d)
        #pragma unroll
        for (int ks = 0; ks < 4; ++ks) {
            bf16x8 pa = *(const bf16x8*)(pb + lrow * 136 + ks * 32 + lgrp * 8);
            #pragma unroll
            for (int nd = 0; nd < 4; ++nd) {
                const size_t voff = (size_t)(nd * 16 + lrow) * T_SEQ + cc * 128 + ks * 32 + lgrp * 8;
                bf16x8 vh = *(const bf16x8*)(vth + voff);
                bf16x8 vl = *(const bf16x8*)(vtl + voff);
                f32x4 a = o[nd];
                a = __builtin_amdgcn_mfma_f32_16x16x32_bf16(pa, vh, a, 0, 0, 0);
                a = __builtin_amdgcn_mfma_f32_16x16x32_bf16(pa, vl, a, 0, 0, 0);
                o[nd] = a;
            }
        }
        // attn stores last in chunk (issue and forget; overlap next chunk's MFMA)
        #pragma unroll
        for (int n8 = 0; n8 < 8; ++n8)
            __builtin_nontemporal_store(s[n8], (f32x4*)(arow + cc * 128 + n8 * 16));
    }

    // --- out store: lane holds out[t0 + lgrp*4 + j][nd*16 + lrow], already normalized ---
    #pragma unroll
    for (int nd = 0; nd < 4; ++nd)
        #pragma unroll
        for (int j = 0; j < 4; ++j)
            __builtin_nontemporal_store(o[nd][j],
                out + base + (size_t)(t0 + lgrp * 4 + j) * D_HEAD + nd * 16 + lrow);
}

extern "C" void kernel_launch(void* const* d_in, const int* in_sizes, int n_in,
                              void* d_out, int out_size, void* d_ws, size_t ws_size,
                              hipStream_t stream) {
    const float* q = (const float*)d_in[0];
    const float* k = (const float*)d_in[1];
    const float* v = (const float*)d_in[2];
    float* out  = (float*)d_out;
    float* attn = out + (size_t)OUT_ELEMS;

    // d_ws layout
    float* ctab = (float*)d_ws;                                  // T*32 f32
    float* stab = ctab + T_SEQ * 32;                             // T*32 f32
    unsigned short* wsu = (unsigned short*)(stab + T_SEQ * 32);
    const size_t NE = (size_t)BH_N * T_SEQ * D_HEAD;             // 4,194,304
    unsigned short* Qh  = wsu + 0 * NE;
    unsigned short* Ql  = wsu + 1 * NE;
    unsigned short* Kh  = wsu + 2 * NE;
    unsigned short* Kl  = wsu + 3 * NE;
    unsigned short* Vth = wsu + 4 * NE;
    unsigned short* Vtl = wsu + 5 * NE;                          // total ws ~48.5 MB

    rope_table_kernel<<<dim3((T_SEQ * 32 + 255) / 256), dim3(256), 0, stream>>>(ctab, stab);
    ropesplit_kernel<<<dim3(BH_N * T_SEQ / 16), dim3(256), 0, stream>>>(q, ctab, stab, Qh, Ql, 0.125f);
    ropesplit_kernel<<<dim3(BH_N * T_SEQ / 16), dim3(256), 0, stream>>>(k, ctab, stab, Kh, Kl, 1.0f);
    vtrans_kernel<<<dim3(T_SEQ / 64, BH_N), dim3(256), 0, stream>>>(v, Vth, Vtl);
    attn_mfma_kernel<<<dim3(BH_N * T_SEQ / 64), dim3(256), 0, stream>>>(Qh, Ql, Kh, Kl, Vth, Vtl, out, attn);
}

// Round 6
// 214.978 us; speedup vs baseline: 2.8676x; 2.8676x over previous
//
#include <hip/hip_runtime.h>
#include <hip/hip_bf16.h>
#include <math.h>

// B=2,H=16 (BH=32), T=2048, D=64. fp32 in/out.
// d_out = [out (BH*T*64) | attn (BH*T*T)] fp32.
//
// R6: plain-bf16 (no hi/lo compensation), two-pass, global_load_lds staged.
//  - block = 4 waves, 64 q-rows (wave w: 16 rows), all 2048 cols per wave.
//  - K chunk (64x64 bf16) + V^T chunk (64x64) staged via global_load_lds
//    (width 16) into XOR-swizzled LDS, double-buffered; zero VGPR cost.
//  - raw s_barrier + counted vmcnt(4): attn nt-stores ride across barriers,
//    never force-drained in-loop (stores issued AFTER next-tile stage).
//  - pass A: QK^T -> exp -> rowsum. pass B: QK^T -> exp*inv -> attn stores
//    + PV via pbuf roundtrip. All reductions wave-local (shfl).

#define T_SEQ  2048
#define D_HEAD 64
#define BH_N   32
#define NCH    32            // 64-col chunks
#define OUT_ELEMS (BH_N * T_SEQ * D_HEAD)

typedef __attribute__((ext_vector_type(8))) short bf16x8;
typedef __attribute__((ext_vector_type(4))) float f32x4;

__device__ __forceinline__ unsigned short f2bf(float x) {
    __hip_bfloat16 h = __float2bfloat16(x);
    return *reinterpret_cast<unsigned short*>(&h);
}

// bank swizzle: XOR byte-bits 4-6 with (128B-row & 7); involution
__device__ __forceinline__ int swz(int o) { return o ^ (((o >> 7) & 7) << 4); }

// ---------------- precompute: rope tables ----------------
__global__ void rope_table_kernel(float* __restrict__ ctab, float* __restrict__ stab) {
    int i = blockIdx.x * blockDim.x + threadIdx.x;
    if (i >= T_SEQ * 32) return;
    int t = i >> 5;
    int j = i & 31;
    float invf = powf(10000.0f, -(float)j / 32.0f);
    float a = (float)t * invf;
    ctab[i] = cosf(a);
    stab[i] = sinf(a);
}

// ---------------- precompute: rope -> bf16 ----------------
__global__ __launch_bounds__(256)
void ropebf16_kernel(const float* __restrict__ X, const float* __restrict__ ctab,
                     const float* __restrict__ stab, unsigned short* __restrict__ H,
                     float scale)
{
    const int r  = blockIdx.x * 16 + (threadIdx.x >> 4);
    const int c4 = threadIdx.x & 15;
    const int t  = r & (T_SEQ - 1);
    const float4* xr = (const float4*)(X + (size_t)r * 64);
    float4 a = xr[c4];
    float4 b = xr[c4 ^ 8];
    float4 c = ((const float4*)(ctab + t * 32))[c4 & 7];
    float4 s = ((const float4*)(stab + t * 32))[c4 & 7];
    float4 ro;
    if (c4 < 8) {
        ro.x = a.x * c.x - b.x * s.x; ro.y = a.y * c.y - b.y * s.y;
        ro.z = a.z * c.z - b.z * s.z; ro.w = a.w * c.w - b.w * s.w;
    } else {
        ro.x = a.x * c.x + b.x * s.x; ro.y = a.y * c.y + b.y * s.y;
        ro.z = a.z * c.z + b.z * s.z; ro.w = a.w * c.w + b.w * s.w;
    }
    ushort4 h;
    h.x = f2bf(ro.x * scale); h.y = f2bf(ro.y * scale);
    h.z = f2bf(ro.z * scale); h.w = f2bf(ro.w * scale);
    *(ushort4*)(H + (size_t)r * 64 + c4 * 4) = h;
}

// ---------------- precompute: V transpose -> bf16 [bh][64][T] ----------------
__global__ __launch_bounds__(256)
void vtbf16_kernel(const float* __restrict__ V, unsigned short* __restrict__ Vt)
{
    __shared__ float tile[64][65];
    const int bh = blockIdx.y;
    const int tt = blockIdx.x;
    const float* vg = V + ((size_t)bh * T_SEQ + tt * 64) * 64;
    #pragma unroll
    for (int i = 0; i < 4; ++i) {
        const int row = (threadIdx.x >> 4) + i * 16;
        const int c4  = threadIdx.x & 15;
        float4 a = *(const float4*)(vg + (size_t)row * 64 + c4 * 4);
        tile[row][c4 * 4 + 0] = a.x; tile[row][c4 * 4 + 1] = a.y;
        tile[row][c4 * 4 + 2] = a.z; tile[row][c4 * 4 + 3] = a.w;
    }
    __syncthreads();
    #pragma unroll
    for (int i = 0; i < 4; ++i) {
        const int d   = (threadIdx.x >> 4) + i * 16;
        const int tc4 = threadIdx.x & 15;
        ushort4 h;
        h.x = f2bf(tile[tc4 * 4 + 0][d]);
        h.y = f2bf(tile[tc4 * 4 + 1][d]);
        h.z = f2bf(tile[tc4 * 4 + 2][d]);
        h.w = f2bf(tile[tc4 * 4 + 3][d]);
        *(ushort4*)(Vt + ((size_t)bh * 64 + d) * T_SEQ + tt * 64 + tc4 * 4) = h;
    }
}

// ---------------- main attention kernel ----------------
__global__ __launch_bounds__(256, 3)
void attn_mfma_kernel(const unsigned short* __restrict__ Qb,
                      const unsigned short* __restrict__ Kb,
                      const unsigned short* __restrict__ Vt,
                      float* __restrict__ out, float* __restrict__ attn)
{
    __shared__ __align__(16) unsigned short kbuf[2][64][64];   // 16 KB
    __shared__ __align__(16) unsigned short vbuf[2][64][64];   // 16 KB
    __shared__ __align__(16) unsigned short pbuf[4][16][72];   // 9 KB

    const int tid  = threadIdx.x;
    const int lane = tid & 63;
    const int w    = tid >> 6;
    const int lrow = lane & 15;
    const int lgrp = lane >> 4;

    // XCD swizzle: 1024 blocks = 8 XCD * 128; 4 bh per XCD (K/V L2-resident)
    const int lid = blockIdx.x;
    const int vid = (lid & 7) * 128 + (lid >> 3);
    const int bh  = vid >> 5;
    const int m   = vid & 31;
    const int t0  = m * 64 + w * 16;       // this wave's first q-row

    const size_t base = (size_t)bh * T_SEQ * D_HEAD;
    const char* kgb = (const char*)(Kb + base);           // [2048][64] bf16, 128B rows
    const char* vgb = (const char*)(Vt + (size_t)bh * 64 * T_SEQ);  // [64][2048] bf16, 4096B rows

    // Q B-frags (col = lrow = q-row, k = lgrp*8..)
    bf16x8 qf0, qf1;
    {
        const unsigned short* qp = Qb + base + (size_t)(t0 + lrow) * 64 + lgrp * 8;
        qf0 = *(const bf16x8*)(qp);
        qf1 = *(const bf16x8*)(qp + 32);
    }

    // staging offsets: per wave 2 issues x 1024 B per tile half
    const int so0 = w * 1024 + lane * 16;
    const int so1 = so0 + 4096;
    const int sq0 = swz(so0);
    const int sq1 = swz(so1);
    char* klds = (char*)&kbuf[0][0][0];
    char* vlds = (char*)&vbuf[0][0][0];
    char* plds = (char*)&pbuf[w][0][0];

#define STAGE_K(b, cc) do { \
    __builtin_amdgcn_global_load_lds((const unsigned int*)(kgb + (size_t)(cc) * 8192 + sq0), \
        (unsigned int*)(klds + (b) * 8192 + w * 1024), 16, 0, 0); \
    __builtin_amdgcn_global_load_lds((const unsigned int*)(kgb + (size_t)(cc) * 8192 + sq1), \
        (unsigned int*)(klds + (b) * 8192 + 4096 + w * 1024), 16, 0, 0); \
} while (0)

#define STAGE_V(b, cc) do { \
    __builtin_amdgcn_global_load_lds((const unsigned int*)(vgb + (size_t)(sq0 >> 7) * 4096 + (cc) * 128 + (sq0 & 127)), \
        (unsigned int*)(vlds + (b) * 8192 + w * 1024), 16, 0, 0); \
    __builtin_amdgcn_global_load_lds((const unsigned int*)(vgb + (size_t)(sq1 >> 7) * 4096 + (cc) * 128 + (sq1 & 127)), \
        (unsigned int*)(vlds + (b) * 8192 + 4096 + w * 1024), 16, 0, 0); \
} while (0)

    // ================= pass A: rowsum =================
    float rp = 0.f;
    STAGE_K(0, 0);
    for (int cc = 0; cc < NCH; ++cc) {
        const int p = cc & 1;
        asm volatile("s_waitcnt vmcnt(0)" ::: "memory");   // my K stage for cc done
        __builtin_amdgcn_s_barrier();                      // all waves' stage done
        if (cc + 1 < NCH) STAGE_K(p ^ 1, cc + 1);
        __builtin_amdgcn_sched_barrier(0);
        const char* kb = klds + p * 8192;
        #pragma unroll
        for (int nt = 0; nt < 4; ++nt) {
            const int o = (nt * 16 + lrow) * 128 + lgrp * 16;
            bf16x8 a0 = *(const bf16x8*)(kb + swz(o));
            bf16x8 a1 = *(const bf16x8*)(kb + swz(o + 64));
            f32x4 acc = (f32x4){0.f, 0.f, 0.f, 0.f};
            acc = __builtin_amdgcn_mfma_f32_16x16x32_bf16(a0, qf0, acc, 0, 0, 0);
            acc = __builtin_amdgcn_mfma_f32_16x16x32_bf16(a1, qf1, acc, 0, 0, 0);
            rp += __expf(acc[0]) + __expf(acc[1]) + __expf(acc[2]) + __expf(acc[3]);
        }
        asm volatile("s_waitcnt lgkmcnt(0)" ::: "memory"); // my tile reads done
        __builtin_amdgcn_s_barrier();                      // all waves done reading
    }
    rp += __shfl_xor(rp, 16, 64);
    rp += __shfl_xor(rp, 32, 64);
    const float inv = 1.0f / rp;

    // ================= pass B: attn + PV =================
    f32x4 o4[4];
    #pragma unroll
    for (int nd = 0; nd < 4; ++nd) o4[nd] = (f32x4){0.f, 0.f, 0.f, 0.f};

    float* arow = attn + (size_t)bh * T_SEQ * T_SEQ + (size_t)(t0 + lrow) * T_SEQ + lgrp * 4;

    STAGE_K(0, 0);
    STAGE_V(0, 0);
    asm volatile("s_waitcnt vmcnt(0)" ::: "memory");       // prologue drain

    for (int cc = 0; cc < NCH; ++cc) {
        const int p = cc & 1;
        // gll(cc) are the 4 oldest vmem ops; allow 4 youngest (stores cc-1) in flight
        asm volatile("s_waitcnt vmcnt(4)" ::: "memory");
        __builtin_amdgcn_s_barrier();
        if (cc + 1 < NCH) { STAGE_K(p ^ 1, cc + 1); STAGE_V(p ^ 1, cc + 1); }
        __builtin_amdgcn_sched_barrier(0);                 // keep gll ahead of stores

        const char* kb = klds + p * 8192;
        const char* vb = vlds + p * 8192;

        // QK^T: lane -> S[q=lrow][s = nt*16 + lgrp*4 + j]
        f32x4 s4[4];
        #pragma unroll
        for (int nt = 0; nt < 4; ++nt) {
            const int o = (nt * 16 + lrow) * 128 + lgrp * 16;
            bf16x8 a0 = *(const bf16x8*)(kb + swz(o));
            bf16x8 a1 = *(const bf16x8*)(kb + swz(o + 64));
            f32x4 acc = (f32x4){0.f, 0.f, 0.f, 0.f};
            acc = __builtin_amdgcn_mfma_f32_16x16x32_bf16(a0, qf0, acc, 0, 0, 0);
            acc = __builtin_amdgcn_mfma_f32_16x16x32_bf16(a1, qf1, acc, 0, 0, 0);
            s4[nt] = acc;
        }
        // normalized P
        #pragma unroll
        for (int nt = 0; nt < 4; ++nt) {
            s4[nt][0] = __expf(s4[nt][0]) * inv;
            s4[nt][1] = __expf(s4[nt][1]) * inv;
            s4[nt][2] = __expf(s4[nt][2]) * inv;
            s4[nt][3] = __expf(s4[nt][3]) * inv;
        }
        // P -> pbuf (bf16, A-frag layout source)
        #pragma unroll
        for (int nt = 0; nt < 4; ++nt) {
            ushort4 p4;
            p4.x = f2bf(s4[nt][0]); p4.y = f2bf(s4[nt][1]);
            p4.z = f2bf(s4[nt][2]); p4.w = f2bf(s4[nt][3]);
            *(ushort4*)(plds + lrow * 144 + nt * 32 + lgrp * 8) = p4;
        }
        // PV: o4[nd] += P(16q x 64s) * V^T(64s x 64d)
        #pragma unroll
        for (int ks = 0; ks < 2; ++ks) {
            bf16x8 pa = *(const bf16x8*)(plds + lrow * 144 + ks * 64 + lgrp * 16);
            #pragma unroll
            for (int nd = 0; nd < 4; ++nd) {
                const int vo = (nd * 16 + lrow) * 128 + ks * 64 + lgrp * 16;
                bf16x8 vf = *(const bf16x8*)(vb + swz(vo));
                o4[nd] = __builtin_amdgcn_mfma_f32_16x16x32_bf16(pa, vf, o4[nd], 0, 0, 0);
            }
        }
        __builtin_amdgcn_sched_barrier(0);                 // stores stay after gll
        // attn stores (nt, fire-and-forget; ride across barriers via vmcnt(4))
        #pragma unroll
        for (int nt = 0; nt < 4; ++nt)
            __builtin_nontemporal_store(s4[nt], (f32x4*)(arow + cc * 64 + nt * 16));

        asm volatile("s_waitcnt lgkmcnt(0)" ::: "memory");
        __builtin_amdgcn_s_barrier();
    }

    // out store: lane holds out[t0 + lgrp*4 + j][nd*16 + lrow]
    #pragma unroll
    for (int nd = 0; nd < 4; ++nd)
        #pragma unroll
        for (int j = 0; j < 4; ++j)
            __builtin_nontemporal_store(o4[nd][j],
                out + base + (size_t)(t0 + lgrp * 4 + j) * D_HEAD + nd * 16 + lrow);

#undef STAGE_K
#undef STAGE_V
}

extern "C" void kernel_launch(void* const* d_in, const int* in_sizes, int n_in,
                              void* d_out, int out_size, void* d_ws, size_t ws_size,
                              hipStream_t stream) {
    const float* q = (const float*)d_in[0];
    const float* k = (const float*)d_in[1];
    const float* v = (const float*)d_in[2];
    float* out  = (float*)d_out;
    float* attn = out + (size_t)OUT_ELEMS;

    float* ctab = (float*)d_ws;                              // T*32 f32
    float* stab = ctab + T_SEQ * 32;                         // T*32 f32
    unsigned short* wsu = (unsigned short*)(stab + T_SEQ * 32);
    const size_t NE = (size_t)BH_N * T_SEQ * D_HEAD;         // 4,194,304
    unsigned short* Qb = wsu + 0 * NE;
    unsigned short* Kb = wsu + 1 * NE;
    unsigned short* Vt = wsu + 2 * NE;                       // ~25.7 MB total

    rope_table_kernel<<<dim3((T_SEQ * 32 + 255) / 256), dim3(256), 0, stream>>>(ctab, stab);
    ropebf16_kernel<<<dim3(BH_N * T_SEQ / 16), dim3(256), 0, stream>>>(q, ctab, stab, Qb, 0.125f);
    ropebf16_kernel<<<dim3(BH_N * T_SEQ / 16), dim3(256), 0, stream>>>(k, ctab, stab, Kb, 1.0f);
    vtbf16_kernel<<<dim3(T_SEQ / 64, BH_N), dim3(256), 0, stream>>>(v, Vt);
    attn_mfma_kernel<<<dim3(BH_N * T_SEQ / 64), dim3(256), 0, stream>>>(Qb, Kb, Vt, out, attn);
}

// Round 7
// 209.973 us; speedup vs baseline: 2.9359x; 1.0238x over previous
//
#include <hip/hip_runtime.h>
#include <hip/hip_bf16.h>
#include <math.h>

// B=2,H=16 (BH=32), T=2048, D=64. fp32 in/out.
// d_out = [out (BH*T*64) | attn (BH*T*T)] fp32.
//
// R7: two-pass, K gll-staged (triple buffer), V direct-to-reg, 1 barrier/chunk.
//  - block = 4 waves, 64 q-rows; wave owns 16 rows x all 2048 cols.
//  - K chunk (64x64 bf16) staged via global_load_lds w16 into pre-swizzled LDS.
//  - V^T read straight to regs (L2/L3-resident; no LDS, no extra waits).
//  - no explicit vmcnt in pass-B loop: in-order vmcnt retirement through the
//    compiler's PV vload-wait retires each K-stage before its readers' barrier.
//  - 33 KB LDS + launch_bounds(256,4): 4 blocks/CU, 1024 blocks = no tail.

#define T_SEQ  2048
#define D_HEAD 64
#define BH_N   32
#define NCH    32            // 64-col chunks
#define OUT_ELEMS (BH_N * T_SEQ * D_HEAD)

typedef __attribute__((ext_vector_type(8))) short bf16x8;
typedef __attribute__((ext_vector_type(4))) float f32x4;

__device__ __forceinline__ unsigned short f2bf(float x) {
    __hip_bfloat16 h = __float2bfloat16(x);
    return *reinterpret_cast<unsigned short*>(&h);
}

// bank swizzle: XOR byte-bits 4-6 with (128B-row & 7); involution
__device__ __forceinline__ int swz(int o) { return o ^ (((o >> 7) & 7) << 4); }

// ---------------- precompute: rope tables ----------------
__global__ void rope_table_kernel(float* __restrict__ ctab, float* __restrict__ stab) {
    int i = blockIdx.x * blockDim.x + threadIdx.x;
    if (i >= T_SEQ * 32) return;
    int t = i >> 5;
    int j = i & 31;
    float invf = powf(10000.0f, -(float)j / 32.0f);
    float a = (float)t * invf;
    ctab[i] = cosf(a);
    stab[i] = sinf(a);
}

// ---------------- precompute: rope -> bf16 ----------------
__global__ __launch_bounds__(256)
void ropebf16_kernel(const float* __restrict__ X, const float* __restrict__ ctab,
                     const float* __restrict__ stab, unsigned short* __restrict__ H,
                     float scale)
{
    const int r  = blockIdx.x * 16 + (threadIdx.x >> 4);
    const int c4 = threadIdx.x & 15;
    const int t  = r & (T_SEQ - 1);
    const float4* xr = (const float4*)(X + (size_t)r * 64);
    float4 a = xr[c4];
    float4 b = xr[c4 ^ 8];
    float4 c = ((const float4*)(ctab + t * 32))[c4 & 7];
    float4 s = ((const float4*)(stab + t * 32))[c4 & 7];
    float4 ro;
    if (c4 < 8) {
        ro.x = a.x * c.x - b.x * s.x; ro.y = a.y * c.y - b.y * s.y;
        ro.z = a.z * c.z - b.z * s.z; ro.w = a.w * c.w - b.w * s.w;
    } else {
        ro.x = a.x * c.x + b.x * s.x; ro.y = a.y * c.y + b.y * s.y;
        ro.z = a.z * c.z + b.z * s.z; ro.w = a.w * c.w + b.w * s.w;
    }
    ushort4 h;
    h.x = f2bf(ro.x * scale); h.y = f2bf(ro.y * scale);
    h.z = f2bf(ro.z * scale); h.w = f2bf(ro.w * scale);
    *(ushort4*)(H + (size_t)r * 64 + c4 * 4) = h;
}

// ---------------- precompute: V transpose -> bf16 [bh][64][T] ----------------
__global__ __launch_bounds__(256)
void vtbf16_kernel(const float* __restrict__ V, unsigned short* __restrict__ Vt)
{
    __shared__ float tile[64][65];
    const int bh = blockIdx.y;
    const int tt = blockIdx.x;
    const float* vg = V + ((size_t)bh * T_SEQ + tt * 64) * 64;
    #pragma unroll
    for (int i = 0; i < 4; ++i) {
        const int row = (threadIdx.x >> 4) + i * 16;
        const int c4  = threadIdx.x & 15;
        float4 a = *(const float4*)(vg + (size_t)row * 64 + c4 * 4);
        tile[row][c4 * 4 + 0] = a.x; tile[row][c4 * 4 + 1] = a.y;
        tile[row][c4 * 4 + 2] = a.z; tile[row][c4 * 4 + 3] = a.w;
    }
    __syncthreads();
    #pragma unroll
    for (int i = 0; i < 4; ++i) {
        const int d   = (threadIdx.x >> 4) + i * 16;
        const int tc4 = threadIdx.x & 15;
        ushort4 h;
        h.x = f2bf(tile[tc4 * 4 + 0][d]);
        h.y = f2bf(tile[tc4 * 4 + 1][d]);
        h.z = f2bf(tile[tc4 * 4 + 2][d]);
        h.w = f2bf(tile[tc4 * 4 + 3][d]);
        *(ushort4*)(Vt + ((size_t)bh * 64 + d) * T_SEQ + tt * 64 + tc4 * 4) = h;
    }
}

// ---------------- main attention kernel ----------------
__global__ __launch_bounds__(256, 4)
void attn_mfma_kernel(const unsigned short* __restrict__ Qb,
                      const unsigned short* __restrict__ Kb,
                      const unsigned short* __restrict__ Vt,
                      float* __restrict__ out, float* __restrict__ attn)
{
    __shared__ __align__(16) unsigned short kbuf[3][64][64];   // 24 KB
    __shared__ __align__(16) unsigned short pbuf[4][16][72];   // 9 KB

    const int tid  = threadIdx.x;
    const int lane = tid & 63;
    const int w    = tid >> 6;
    const int lrow = lane & 15;
    const int lgrp = lane >> 4;

    // XCD swizzle: 1024 blocks = 8 XCD * 128; 4 bh per XCD
    const int lid = blockIdx.x;
    const int vid = (lid & 7) * 128 + (lid >> 3);
    const int bh  = vid >> 5;
    const int m   = vid & 31;
    const int t0  = m * 64 + w * 16;       // this wave's first q-row

    const size_t base = (size_t)bh * T_SEQ * D_HEAD;
    const char* kgb = (const char*)(Kb + base);                 // [2048][64] bf16
    const unsigned short* vgb = Vt + (size_t)bh * 64 * T_SEQ;   // [64][2048] bf16

    // Q B-frags (col = lrow = q-row, k = lgrp*8..)
    bf16x8 qf0, qf1;
    {
        const unsigned short* qp = Qb + base + (size_t)(t0 + lrow) * 64 + lgrp * 8;
        qf0 = *(const bf16x8*)(qp);
        qf1 = *(const bf16x8*)(qp + 32);
    }

    const int so0 = w * 1024 + lane * 16;
    const int so1 = so0 + 4096;
    const int sq0 = swz(so0);
    const int sq1 = swz(so1);
    char* klds = (char*)&kbuf[0][0][0];
    char* plds = (char*)&pbuf[w][0][0];

#define STAGE_K(b, cc) do { \
    __builtin_amdgcn_global_load_lds((const unsigned int*)(kgb + (size_t)(cc) * 8192 + sq0), \
        (unsigned int*)(klds + (b) * 8192 + w * 1024), 16, 0, 0); \
    __builtin_amdgcn_global_load_lds((const unsigned int*)(kgb + (size_t)(cc) * 8192 + sq1), \
        (unsigned int*)(klds + (b) * 8192 + 4096 + w * 1024), 16, 0, 0); \
} while (0)

    // ================= pass A: rowsum =================
    float rpa0 = 0.f, rpa1 = 0.f, rpa2 = 0.f, rpa3 = 0.f;
    STAGE_K(0, 0);
    STAGE_K(1, 1);
    for (int cc = 0; cc < NCH; ++cc) {
        if (cc < NCH - 1) { asm volatile("s_waitcnt vmcnt(2)" ::: "memory"); }
        else              { asm volatile("s_waitcnt vmcnt(0)" ::: "memory"); }
        __builtin_amdgcn_s_barrier();
        if (cc + 2 < NCH) STAGE_K((cc + 2) % 3, cc + 2);
        __builtin_amdgcn_sched_barrier(0);
        const char* kb = klds + (cc % 3) * 8192;
        #pragma unroll
        for (int nt = 0; nt < 4; ++nt) {
            const int o = (nt * 16 + lrow) * 128 + lgrp * 16;
            bf16x8 a0 = *(const bf16x8*)(kb + swz(o));
            bf16x8 a1 = *(const bf16x8*)(kb + swz(o + 64));
            f32x4 acc = (f32x4){0.f, 0.f, 0.f, 0.f};
            acc = __builtin_amdgcn_mfma_f32_16x16x32_bf16(a0, qf0, acc, 0, 0, 0);
            acc = __builtin_amdgcn_mfma_f32_16x16x32_bf16(a1, qf1, acc, 0, 0, 0);
            rpa0 += __expf(acc[0]); rpa1 += __expf(acc[1]);
            rpa2 += __expf(acc[2]); rpa3 += __expf(acc[3]);
        }
    }
    float rp = (rpa0 + rpa1) + (rpa2 + rpa3);
    rp += __shfl_xor(rp, 16, 64);
    rp += __shfl_xor(rp, 32, 64);
    const float inv = 1.0f / rp;

    // inter-pass barrier: all waves' pass-A LDS reads done before re-staging
    __builtin_amdgcn_sched_barrier(0);
    __builtin_amdgcn_s_barrier();

    // ================= pass B: attn + PV =================
    f32x4 o4[4];
    #pragma unroll
    for (int nd = 0; nd < 4; ++nd) o4[nd] = (f32x4){0.f, 0.f, 0.f, 0.f};

    float* arow = attn + (size_t)bh * T_SEQ * T_SEQ + (size_t)(t0 + lrow) * T_SEQ + lgrp * 4;

    STAGE_K(0, 0);
    STAGE_K(1, 1);
    asm volatile("s_waitcnt vmcnt(2)" ::: "memory");   // gll(0) retired pre-barrier

    for (int cc = 0; cc < NCH; ++cc) {
        __builtin_amdgcn_s_barrier();
        __builtin_amdgcn_sched_barrier(0);             // pin iteration boundary
        // V loads first (oldest vmem this iter -> PV wait retires older glls)
        bf16x8 vf[8];
        #pragma unroll
        for (int nd = 0; nd < 4; ++nd)
            #pragma unroll
            for (int ks = 0; ks < 2; ++ks)
                vf[nd * 2 + ks] = *(const bf16x8*)(vgb + (size_t)(nd * 16 + lrow) * T_SEQ
                                                   + cc * 64 + ks * 32 + lgrp * 8);
        if (cc + 2 < NCH) STAGE_K((cc + 2) % 3, cc + 2);
        __builtin_amdgcn_sched_barrier(0);

        // QK^T from staged K: lane -> S[q=lrow][s = nt*16 + lgrp*4 + j]
        const char* kb = klds + (cc % 3) * 8192;
        f32x4 s4[4];
        #pragma unroll
        for (int nt = 0; nt < 4; ++nt) {
            const int o = (nt * 16 + lrow) * 128 + lgrp * 16;
            bf16x8 a0 = *(const bf16x8*)(kb + swz(o));
            bf16x8 a1 = *(const bf16x8*)(kb + swz(o + 64));
            f32x4 acc = (f32x4){0.f, 0.f, 0.f, 0.f};
            acc = __builtin_amdgcn_mfma_f32_16x16x32_bf16(a0, qf0, acc, 0, 0, 0);
            acc = __builtin_amdgcn_mfma_f32_16x16x32_bf16(a1, qf1, acc, 0, 0, 0);
            s4[nt] = acc;
        }
        // normalized P
        #pragma unroll
        for (int nt = 0; nt < 4; ++nt) {
            s4[nt][0] = __expf(s4[nt][0]) * inv;
            s4[nt][1] = __expf(s4[nt][1]) * inv;
            s4[nt][2] = __expf(s4[nt][2]) * inv;
            s4[nt][3] = __expf(s4[nt][3]) * inv;
        }
        // P -> pbuf (bf16)
        #pragma unroll
        for (int nt = 0; nt < 4; ++nt) {
            ushort4 p4;
            p4.x = f2bf(s4[nt][0]); p4.y = f2bf(s4[nt][1]);
            p4.z = f2bf(s4[nt][2]); p4.w = f2bf(s4[nt][3]);
            *(ushort4*)(plds + lrow * 144 + nt * 32 + lgrp * 8) = p4;
        }
        asm volatile("s_waitcnt lgkmcnt(0)" ::: "memory");
        __builtin_amdgcn_sched_barrier(0);
        // attn stores (fire-and-forget; retired by PV wait next iteration)
        #pragma unroll
        for (int nt = 0; nt < 4; ++nt)
            __builtin_nontemporal_store(s4[nt], (f32x4*)(arow + cc * 64 + nt * 16));
        // PV: o4[nd] += P(16q x 64s) * V^T(64s x 64d)
        #pragma unroll
        for (int ks = 0; ks < 2; ++ks) {
            bf16x8 pa = *(const bf16x8*)(plds + lrow * 144 + ks * 64 + lgrp * 16);
            #pragma unroll
            for (int nd = 0; nd < 4; ++nd)
                o4[nd] = __builtin_amdgcn_mfma_f32_16x16x32_bf16(pa, vf[nd * 2 + ks], o4[nd], 0, 0, 0);
        }
    }

    // out store: lane holds out[t0 + lgrp*4 + j][nd*16 + lrow] (normalized)
    #pragma unroll
    for (int nd = 0; nd < 4; ++nd)
        #pragma unroll
        for (int j = 0; j < 4; ++j)
            __builtin_nontemporal_store(o4[nd][j],
                out + base + (size_t)(t0 + lgrp * 4 + j) * D_HEAD + nd * 16 + lrow);

#undef STAGE_K
}

extern "C" void kernel_launch(void* const* d_in, const int* in_sizes, int n_in,
                              void* d_out, int out_size, void* d_ws, size_t ws_size,
                              hipStream_t stream) {
    const float* q = (const float*)d_in[0];
    const float* k = (const float*)d_in[1];
    const float* v = (const float*)d_in[2];
    float* out  = (float*)d_out;
    float* attn = out + (size_t)OUT_ELEMS;

    float* ctab = (float*)d_ws;                              // T*32 f32
    float* stab = ctab + T_SEQ * 32;                         // T*32 f32
    unsigned short* wsu = (unsigned short*)(stab + T_SEQ * 32);
    const size_t NE = (size_t)BH_N * T_SEQ * D_HEAD;         // 4,194,304
    unsigned short* Qb = wsu + 0 * NE;
    unsigned short* Kb = wsu + 1 * NE;
    unsigned short* Vt = wsu + 2 * NE;                       // ~25.7 MB total

    rope_table_kernel<<<dim3((T_SEQ * 32 + 255) / 256), dim3(256), 0, stream>>>(ctab, stab);
    ropebf16_kernel<<<dim3(BH_N * T_SEQ / 16), dim3(256), 0, stream>>>(q, ctab, stab, Qb, 0.125f);
    ropebf16_kernel<<<dim3(BH_N * T_SEQ / 16), dim3(256), 0, stream>>>(k, ctab, stab, Kb, 1.0f);
    vtbf16_kernel<<<dim3(T_SEQ / 64, BH_N), dim3(256), 0, stream>>>(v, Vt);
    attn_mfma_kernel<<<dim3(BH_N * T_SEQ / 64), dim3(256), 0, stream>>>(Qb, Kb, Vt, out, attn);
}

// Round 8
// 206.754 us; speedup vs baseline: 2.9817x; 1.0156x over previous
//
#include <hip/hip_runtime.h>
#include <hip/hip_bf16.h>
#include <math.h>

// B=2,H=16 (BH=32), T=2048, D=64. fp32 in/out.
// d_out = [out (BH*T*64) | attn (BH*T*T)] fp32.
//
// R8: store-decoupled pipeline + exp2.
//  - iteration order: QK^T -> exp2*inv -> P-LDS -> PV -> Vload(cc+1) ->
//    STAGE_K(cc+2) -> attn stores(cc) -> tail vmcnt(18).
//    Stores are always the YOUNGEST vmem ops; the counted tail wait forces
//    only gll(cc+1)/V(cc)/stores(cc-2) -> each store batch gets ~2 iterations
//    to drain (was: forced every iteration by PV's implicit vmcnt(6)).
//  - Q pre-scaled by 0.125/ln2; raw v_exp_f32 (exp2) -> no per-element mul.
//  - K triple-buffer gll staging, V direct-to-reg (single buffer, WAR-safe).
//  - 33 KB LDS, launch_bounds(256,4): 4 blocks/CU, 1024 blocks, no tail.

#define T_SEQ  2048
#define D_HEAD 64
#define BH_N   32
#define NCH    32            // 64-col chunks
#define OUT_ELEMS (BH_N * T_SEQ * D_HEAD)

typedef __attribute__((ext_vector_type(8))) short bf16x8;
typedef __attribute__((ext_vector_type(4))) float f32x4;

__device__ __forceinline__ unsigned short f2bf(float x) {
    __hip_bfloat16 h = __float2bfloat16(x);
    return *reinterpret_cast<unsigned short*>(&h);
}

// bank swizzle: XOR byte-bits 4-6 with (128B-row & 7); involution
__device__ __forceinline__ int swz(int o) { return o ^ (((o >> 7) & 7) << 4); }

// ---------------- precompute: rope tables ----------------
__global__ void rope_table_kernel(float* __restrict__ ctab, float* __restrict__ stab) {
    int i = blockIdx.x * blockDim.x + threadIdx.x;
    if (i >= T_SEQ * 32) return;
    int t = i >> 5;
    int j = i & 31;
    float invf = powf(10000.0f, -(float)j / 32.0f);
    float a = (float)t * invf;
    ctab[i] = cosf(a);
    stab[i] = sinf(a);
}

// ---------------- precompute: rope -> bf16 ----------------
__global__ __launch_bounds__(256)
void ropebf16_kernel(const float* __restrict__ X, const float* __restrict__ ctab,
                     const float* __restrict__ stab, unsigned short* __restrict__ H,
                     float scale)
{
    const int r  = blockIdx.x * 16 + (threadIdx.x >> 4);
    const int c4 = threadIdx.x & 15;
    const int t  = r & (T_SEQ - 1);
    const float4* xr = (const float4*)(X + (size_t)r * 64);
    float4 a = xr[c4];
    float4 b = xr[c4 ^ 8];
    float4 c = ((const float4*)(ctab + t * 32))[c4 & 7];
    float4 s = ((const float4*)(stab + t * 32))[c4 & 7];
    float4 ro;
    if (c4 < 8) {
        ro.x = a.x * c.x - b.x * s.x; ro.y = a.y * c.y - b.y * s.y;
        ro.z = a.z * c.z - b.z * s.z; ro.w = a.w * c.w - b.w * s.w;
    } else {
        ro.x = a.x * c.x + b.x * s.x; ro.y = a.y * c.y + b.y * s.y;
        ro.z = a.z * c.z + b.z * s.z; ro.w = a.w * c.w + b.w * s.w;
    }
    ushort4 h;
    h.x = f2bf(ro.x * scale); h.y = f2bf(ro.y * scale);
    h.z = f2bf(ro.z * scale); h.w = f2bf(ro.w * scale);
    *(ushort4*)(H + (size_t)r * 64 + c4 * 4) = h;
}

// ---------------- precompute: V transpose -> bf16 [bh][64][T] ----------------
__global__ __launch_bounds__(256)
void vtbf16_kernel(const float* __restrict__ V, unsigned short* __restrict__ Vt)
{
    __shared__ float tile[64][65];
    const int bh = blockIdx.y;
    const int tt = blockIdx.x;
    const float* vg = V + ((size_t)bh * T_SEQ + tt * 64) * 64;
    #pragma unroll
    for (int i = 0; i < 4; ++i) {
        const int row = (threadIdx.x >> 4) + i * 16;
        const int c4  = threadIdx.x & 15;
        float4 a = *(const float4*)(vg + (size_t)row * 64 + c4 * 4);
        tile[row][c4 * 4 + 0] = a.x; tile[row][c4 * 4 + 1] = a.y;
        tile[row][c4 * 4 + 2] = a.z; tile[row][c4 * 4 + 3] = a.w;
    }
    __syncthreads();
    #pragma unroll
    for (int i = 0; i < 4; ++i) {
        const int d   = (threadIdx.x >> 4) + i * 16;
        const int tc4 = threadIdx.x & 15;
        ushort4 h;
        h.x = f2bf(tile[tc4 * 4 + 0][d]);
        h.y = f2bf(tile[tc4 * 4 + 1][d]);
        h.z = f2bf(tile[tc4 * 4 + 2][d]);
        h.w = f2bf(tile[tc4 * 4 + 3][d]);
        *(ushort4*)(Vt + ((size_t)bh * 64 + d) * T_SEQ + tt * 64 + tc4 * 4) = h;
    }
}

// ---------------- main attention kernel ----------------
__global__ __launch_bounds__(256, 4)
void attn_mfma_kernel(const unsigned short* __restrict__ Qb,
                      const unsigned short* __restrict__ Kb,
                      const unsigned short* __restrict__ Vt,
                      float* __restrict__ out, float* __restrict__ attn)
{
    __shared__ __align__(16) unsigned short kbuf[3][64][64];   // 24 KB
    __shared__ __align__(16) unsigned short pbuf[4][16][72];   // 9 KB

    const int tid  = threadIdx.x;
    const int lane = tid & 63;
    const int w    = tid >> 6;
    const int lrow = lane & 15;
    const int lgrp = lane >> 4;

    // XCD swizzle: 1024 blocks = 8 XCD * 128; 4 bh per XCD
    const int lid = blockIdx.x;
    const int vid = (lid & 7) * 128 + (lid >> 3);
    const int bh  = vid >> 5;
    const int m   = vid & 31;
    const int t0  = m * 64 + w * 16;       // this wave's first q-row

    const size_t base = (size_t)bh * T_SEQ * D_HEAD;
    const char* kgb = (const char*)(Kb + base);                 // [2048][64] bf16
    const unsigned short* vgb = Vt + (size_t)bh * 64 * T_SEQ;   // [64][2048] bf16

    // Q B-frags (col = lrow = q-row, k = lgrp*8..)
    bf16x8 qf0, qf1;
    {
        const unsigned short* qp = Qb + base + (size_t)(t0 + lrow) * 64 + lgrp * 8;
        qf0 = *(const bf16x8*)(qp);
        qf1 = *(const bf16x8*)(qp + 32);
    }

    const int so0 = w * 1024 + lane * 16;
    const int so1 = so0 + 4096;
    const int sq0 = swz(so0);
    const int sq1 = swz(so1);
    char* klds = (char*)&kbuf[0][0][0];
    char* plds = (char*)&pbuf[w][0][0];

#define STAGE_K(b, cc) do { \
    __builtin_amdgcn_global_load_lds((const unsigned int*)(kgb + (size_t)(cc) * 8192 + sq0), \
        (unsigned int*)(klds + (b) * 8192 + w * 1024), 16, 0, 0); \
    __builtin_amdgcn_global_load_lds((const unsigned int*)(kgb + (size_t)(cc) * 8192 + sq1), \
        (unsigned int*)(klds + (b) * 8192 + 4096 + w * 1024), 16, 0, 0); \
} while (0)

    // ================= pass A: rowsum =================
    float rpa0 = 0.f, rpa1 = 0.f, rpa2 = 0.f, rpa3 = 0.f;
    STAGE_K(0, 0);
    STAGE_K(1, 1);
    for (int cc = 0; cc < NCH; ++cc) {
        if (cc < NCH - 1) { asm volatile("s_waitcnt vmcnt(2)" ::: "memory"); }
        else              { asm volatile("s_waitcnt vmcnt(0)" ::: "memory"); }
        __builtin_amdgcn_s_barrier();
        if (cc + 2 < NCH) STAGE_K((cc + 2) % 3, cc + 2);
        __builtin_amdgcn_sched_barrier(0);
        const char* kb = klds + (cc % 3) * 8192;
        #pragma unroll
        for (int nt = 0; nt < 4; ++nt) {
            const int o = (nt * 16 + lrow) * 128 + lgrp * 16;
            bf16x8 a0 = *(const bf16x8*)(kb + swz(o));
            bf16x8 a1 = *(const bf16x8*)(kb + swz(o + 64));
            f32x4 acc = (f32x4){0.f, 0.f, 0.f, 0.f};
            acc = __builtin_amdgcn_mfma_f32_16x16x32_bf16(a0, qf0, acc, 0, 0, 0);
            acc = __builtin_amdgcn_mfma_f32_16x16x32_bf16(a1, qf1, acc, 0, 0, 0);
            rpa0 += __builtin_amdgcn_exp2f(acc[0]);
            rpa1 += __builtin_amdgcn_exp2f(acc[1]);
            rpa2 += __builtin_amdgcn_exp2f(acc[2]);
            rpa3 += __builtin_amdgcn_exp2f(acc[3]);
        }
    }
    float rp = (rpa0 + rpa1) + (rpa2 + rpa3);
    rp += __shfl_xor(rp, 16, 64);
    rp += __shfl_xor(rp, 32, 64);
    const float inv = 1.0f / rp;

    // inter-pass barrier: all waves' pass-A LDS reads done before re-staging
    __builtin_amdgcn_sched_barrier(0);
    __builtin_amdgcn_s_barrier();

    // ================= pass B: attn + PV =================
    f32x4 o4[4];
    #pragma unroll
    for (int nd = 0; nd < 4; ++nd) o4[nd] = (f32x4){0.f, 0.f, 0.f, 0.f};

    float* arow = attn + (size_t)bh * T_SEQ * T_SEQ + (size_t)(t0 + lrow) * T_SEQ + lgrp * 4;

    // prologue: K stages then V(0); force gll(0) done (allow gll(1)+V(0)=10)
    STAGE_K(0, 0);
    STAGE_K(1, 1);
    bf16x8 vf[8];
    #pragma unroll
    for (int nd = 0; nd < 4; ++nd)
        #pragma unroll
        for (int ks = 0; ks < 2; ++ks)
            vf[nd * 2 + ks] = *(const bf16x8*)(vgb + (size_t)(nd * 16 + lrow) * T_SEQ
                                               + ks * 32 + lgrp * 8);
    asm volatile("s_waitcnt vmcnt(10)" ::: "memory");

    for (int cc = 0; cc < NCH; ++cc) {
        __builtin_amdgcn_s_barrier();
        __builtin_amdgcn_sched_barrier(0);

        // QK^T from staged K: lane -> S[q=lrow][s = nt*16 + lgrp*4 + j]
        const char* kb = klds + (cc % 3) * 8192;
        f32x4 s4[4];
        #pragma unroll
        for (int nt = 0; nt < 4; ++nt) {
            const int o = (nt * 16 + lrow) * 128 + lgrp * 16;
            bf16x8 a0 = *(const bf16x8*)(kb + swz(o));
            bf16x8 a1 = *(const bf16x8*)(kb + swz(o + 64));
            f32x4 acc = (f32x4){0.f, 0.f, 0.f, 0.f};
            acc = __builtin_amdgcn_mfma_f32_16x16x32_bf16(a0, qf0, acc, 0, 0, 0);
            acc = __builtin_amdgcn_mfma_f32_16x16x32_bf16(a1, qf1, acc, 0, 0, 0);
            s4[nt] = acc;
        }
        // normalized P via exp2 (Q pre-scaled by 0.125/ln2)
        #pragma unroll
        for (int nt = 0; nt < 4; ++nt) {
            s4[nt][0] = __builtin_amdgcn_exp2f(s4[nt][0]) * inv;
            s4[nt][1] = __builtin_amdgcn_exp2f(s4[nt][1]) * inv;
            s4[nt][2] = __builtin_amdgcn_exp2f(s4[nt][2]) * inv;
            s4[nt][3] = __builtin_amdgcn_exp2f(s4[nt][3]) * inv;
        }
        // P -> pbuf (bf16)
        #pragma unroll
        for (int nt = 0; nt < 4; ++nt) {
            ushort4 p4;
            p4.x = f2bf(s4[nt][0]); p4.y = f2bf(s4[nt][1]);
            p4.z = f2bf(s4[nt][2]); p4.w = f2bf(s4[nt][3]);
            *(ushort4*)(plds + lrow * 144 + nt * 32 + lgrp * 8) = p4;
        }
        asm volatile("s_waitcnt lgkmcnt(0)" ::: "memory");
        __builtin_amdgcn_sched_barrier(0);
        // PV: o4[nd] += P(16q x 64s) * V^T(64s x 64d)  (vf staged last iter)
        #pragma unroll
        for (int ks = 0; ks < 2; ++ks) {
            bf16x8 pa = *(const bf16x8*)(plds + lrow * 144 + ks * 64 + lgrp * 16);
            #pragma unroll
            for (int nd = 0; nd < 4; ++nd)
                o4[nd] = __builtin_amdgcn_mfma_f32_16x16x32_bf16(pa, vf[nd * 2 + ks], o4[nd], 0, 0, 0);
        }
        __builtin_amdgcn_sched_barrier(0);
        // V loads for cc+1 (WAR-safe after PV), then K stage, then stores:
        // stores stay the YOUNGEST vmem ops -> 2 iterations of drain slack.
        if (cc + 1 < NCH) {
            #pragma unroll
            for (int nd = 0; nd < 4; ++nd)
                #pragma unroll
                for (int ks = 0; ks < 2; ++ks)
                    vf[nd * 2 + ks] = *(const bf16x8*)(vgb + (size_t)(nd * 16 + lrow) * T_SEQ
                                                       + (cc + 1) * 64 + ks * 32 + lgrp * 8);
        }
        if (cc + 2 < NCH) STAGE_K((cc + 2) % 3, cc + 2);
        __builtin_amdgcn_sched_barrier(0);
        #pragma unroll
        for (int nt = 0; nt < 4; ++nt)
            __builtin_nontemporal_store(s4[nt], (f32x4*)(arow + cc * 64 + nt * 16));
        __builtin_amdgcn_sched_barrier(0);
        // tail wait: force gll(cc+1) (+older) done before next barrier;
        // allow [stores(cc)=4, STAGE(cc+2)=2, V(cc+1)=8, stores(cc-1)=4] = 18
        if (cc < NCH - 2)      { asm volatile("s_waitcnt vmcnt(18)" ::: "memory"); }
        else if (cc < NCH - 1) { asm volatile("s_waitcnt vmcnt(16)" ::: "memory"); }
    }

    // out store: lane holds out[t0 + lgrp*4 + j][nd*16 + lrow] (normalized)
    #pragma unroll
    for (int nd = 0; nd < 4; ++nd)
        #pragma unroll
        for (int j = 0; j < 4; ++j)
            __builtin_nontemporal_store(o4[nd][j],
                out + base + (size_t)(t0 + lgrp * 4 + j) * D_HEAD + nd * 16 + lrow);

#undef STAGE_K
}

extern "C" void kernel_launch(void* const* d_in, const int* in_sizes, int n_in,
                              void* d_out, int out_size, void* d_ws, size_t ws_size,
                              hipStream_t stream) {
    const float* q = (const float*)d_in[0];
    const float* k = (const float*)d_in[1];
    const float* v = (const float*)d_in[2];
    float* out  = (float*)d_out;
    float* attn = out + (size_t)OUT_ELEMS;

    float* ctab = (float*)d_ws;                              // T*32 f32
    float* stab = ctab + T_SEQ * 32;                         // T*32 f32
    unsigned short* wsu = (unsigned short*)(stab + T_SEQ * 32);
    const size_t NE = (size_t)BH_N * T_SEQ * D_HEAD;         // 4,194,304
    unsigned short* Qb = wsu + 0 * NE;
    unsigned short* Kb = wsu + 1 * NE;
    unsigned short* Vt = wsu + 2 * NE;                       // ~25.7 MB total

    const float QSCALE = 0.18033688011112042f;               // 0.125 / ln(2)

    rope_table_kernel<<<dim3((T_SEQ * 32 + 255) / 256), dim3(256), 0, stream>>>(ctab, stab);
    ropebf16_kernel<<<dim3(BH_N * T_SEQ / 16), dim3(256), 0, stream>>>(q, ctab, stab, Qb, QSCALE);
    ropebf16_kernel<<<dim3(BH_N * T_SEQ / 16), dim3(256), 0, stream>>>(k, ctab, stab, Kb, 1.0f);
    vtbf16_kernel<<<dim3(T_SEQ / 64, BH_N), dim3(256), 0, stream>>>(v, Vt);
    attn_mfma_kernel<<<dim3(BH_N * T_SEQ / 64), dim3(256), 0, stream>>>(Qb, Kb, Vt, out, attn);
}

// Round 9
// 183.496 us; speedup vs baseline: 3.3596x; 1.1268x over previous
//
#include <hip/hip_runtime.h>
#include <hip/hip_bf16.h>
#include <math.h>

// B=2,H=16 (BH=32), T=2048, D=64. fp32 in/out.
// d_out = [out (BH*T*64) | attn (BH*T*T)] fp32.
//
// R9: row-contiguous attn stores via in-LDS f32 P-transpose.
//  - per chunk, wave writes its 16x64 f32 P tile into swizzled tbuf, reads
//    back row-major: one store inst = 4 rows x 256B contiguous (was 16 x 64B).
//  - PV A-frags read from the same tbuf (f32->bf16 cvt in regs); pbuf gone.
//  - K triple-buffer gll staging, V direct-to-reg prefetch, stores youngest,
//    tail vmcnt(18)/(16) forcing only the next K-stage (R8 skeleton).
//  - LDS 24KB kbuf + 16KB tbuf = 40KB -> 4 blocks/CU at 256 threads.

#define T_SEQ  2048
#define D_HEAD 64
#define BH_N   32
#define NCH    32            // 64-col chunks
#define OUT_ELEMS (BH_N * T_SEQ * D_HEAD)

typedef __attribute__((ext_vector_type(8))) short bf16x8;
typedef __attribute__((ext_vector_type(4))) float f32x4;

__device__ __forceinline__ unsigned short f2bf(float x) {
    __hip_bfloat16 h = __float2bfloat16(x);
    return *reinterpret_cast<unsigned short*>(&h);
}

// K-stage bank swizzle: XOR byte-bits 4-6 with (128B-row & 7); involution
__device__ __forceinline__ int swz(int o) { return o ^ (((o >> 7) & 7) << 4); }
// tbuf swizzle: row stride 256B, XOR 16B-slot with (row&7)
__device__ __forceinline__ int tswz(int row, int bcol) {
    return row * 256 + (bcol ^ ((row & 7) << 4));
}

// ---------------- precompute: rope tables ----------------
__global__ void rope_table_kernel(float* __restrict__ ctab, float* __restrict__ stab) {
    int i = blockIdx.x * blockDim.x + threadIdx.x;
    if (i >= T_SEQ * 32) return;
    int t = i >> 5;
    int j = i & 31;
    float invf = powf(10000.0f, -(float)j / 32.0f);
    float a = (float)t * invf;
    ctab[i] = cosf(a);
    stab[i] = sinf(a);
}

// ---------------- precompute: rope -> bf16 (q and k in one launch) ----------------
__global__ __launch_bounds__(256)
void ropebf16_kernel(const float* __restrict__ Q, const float* __restrict__ K,
                     const float* __restrict__ ctab, const float* __restrict__ stab,
                     unsigned short* __restrict__ Qb, unsigned short* __restrict__ Kb,
                     float qscale)
{
    const int r  = blockIdx.x * 16 + (threadIdx.x >> 4);
    const int c4 = threadIdx.x & 15;
    const int t  = r & (T_SEQ - 1);
    const float* X = blockIdx.y ? K : Q;
    unsigned short* H = blockIdx.y ? Kb : Qb;
    const float scale = blockIdx.y ? 1.0f : qscale;
    const float4* xr = (const float4*)(X + (size_t)r * 64);
    float4 a = xr[c4];
    float4 b = xr[c4 ^ 8];
    float4 c = ((const float4*)(ctab + t * 32))[c4 & 7];
    float4 s = ((const float4*)(stab + t * 32))[c4 & 7];
    float4 ro;
    if (c4 < 8) {
        ro.x = a.x * c.x - b.x * s.x; ro.y = a.y * c.y - b.y * s.y;
        ro.z = a.z * c.z - b.z * s.z; ro.w = a.w * c.w - b.w * s.w;
    } else {
        ro.x = a.x * c.x + b.x * s.x; ro.y = a.y * c.y + b.y * s.y;
        ro.z = a.z * c.z + b.z * s.z; ro.w = a.w * c.w + b.w * s.w;
    }
    ushort4 h;
    h.x = f2bf(ro.x * scale); h.y = f2bf(ro.y * scale);
    h.z = f2bf(ro.z * scale); h.w = f2bf(ro.w * scale);
    *(ushort4*)(H + (size_t)r * 64 + c4 * 4) = h;
}

// ---------------- precompute: V transpose -> bf16 [bh][64][T] ----------------
__global__ __launch_bounds__(256)
void vtbf16_kernel(const float* __restrict__ V, unsigned short* __restrict__ Vt)
{
    __shared__ float tile[64][65];
    const int bh = blockIdx.y;
    const int tt = blockIdx.x;
    const float* vg = V + ((size_t)bh * T_SEQ + tt * 64) * 64;
    #pragma unroll
    for (int i = 0; i < 4; ++i) {
        const int row = (threadIdx.x >> 4) + i * 16;
        const int c4  = threadIdx.x & 15;
        float4 a = *(const float4*)(vg + (size_t)row * 64 + c4 * 4);
        tile[row][c4 * 4 + 0] = a.x; tile[row][c4 * 4 + 1] = a.y;
        tile[row][c4 * 4 + 2] = a.z; tile[row][c4 * 4 + 3] = a.w;
    }
    __syncthreads();
    #pragma unroll
    for (int i = 0; i < 4; ++i) {
        const int d   = (threadIdx.x >> 4) + i * 16;
        const int tc4 = threadIdx.x & 15;
        ushort4 h;
        h.x = f2bf(tile[tc4 * 4 + 0][d]);
        h.y = f2bf(tile[tc4 * 4 + 1][d]);
        h.z = f2bf(tile[tc4 * 4 + 2][d]);
        h.w = f2bf(tile[tc4 * 4 + 3][d]);
        *(ushort4*)(Vt + ((size_t)bh * 64 + d) * T_SEQ + tt * 64 + tc4 * 4) = h;
    }
}

// ---------------- main attention kernel ----------------
__global__ __launch_bounds__(256, 4)
void attn_mfma_kernel(const unsigned short* __restrict__ Qb,
                      const unsigned short* __restrict__ Kb,
                      const unsigned short* __restrict__ Vt,
                      float* __restrict__ out, float* __restrict__ attn)
{
    __shared__ __align__(16) unsigned short kbuf[3][64][64];   // 24 KB
    __shared__ __align__(16) float tbuf[4][16 * 64];           // 16 KB (swizzled)

    const int tid  = threadIdx.x;
    const int lane = tid & 63;
    const int w    = tid >> 6;
    const int lrow = lane & 15;
    const int lgrp = lane >> 4;

    // XCD swizzle: 1024 blocks = 8 XCD * 128; 4 bh per XCD
    const int lid = blockIdx.x;
    const int vid = (lid & 7) * 128 + (lid >> 3);
    const int bh  = vid >> 5;
    const int m   = vid & 31;
    const int t0  = m * 64 + w * 16;       // this wave's first q-row

    const size_t base = (size_t)bh * T_SEQ * D_HEAD;
    const char* kgb = (const char*)(Kb + base);                 // [2048][64] bf16
    const unsigned short* vgb = Vt + (size_t)bh * 64 * T_SEQ;   // [64][2048] bf16

    // Q B-frags (col = lrow = q-row, k = lgrp*8..)
    bf16x8 qf0, qf1;
    {
        const unsigned short* qp = Qb + base + (size_t)(t0 + lrow) * 64 + lgrp * 8;
        qf0 = *(const bf16x8*)(qp);
        qf1 = *(const bf16x8*)(qp + 32);
    }

    const int so0 = w * 1024 + lane * 16;
    const int so1 = so0 + 4096;
    const int sq0 = swz(so0);
    const int sq1 = swz(so1);
    char* klds = (char*)&kbuf[0][0][0];
    char* tlds = (char*)&tbuf[w][0];

#define STAGE_K(b, cc) do { \
    __builtin_amdgcn_global_load_lds((const unsigned int*)(kgb + (size_t)(cc) * 8192 + sq0), \
        (unsigned int*)(klds + (b) * 8192 + w * 1024), 16, 0, 0); \
    __builtin_amdgcn_global_load_lds((const unsigned int*)(kgb + (size_t)(cc) * 8192 + sq1), \
        (unsigned int*)(klds + (b) * 8192 + 4096 + w * 1024), 16, 0, 0); \
} while (0)

    // ================= pass A: rowsum =================
    float rpa0 = 0.f, rpa1 = 0.f, rpa2 = 0.f, rpa3 = 0.f;
    STAGE_K(0, 0);
    STAGE_K(1, 1);
    for (int cc = 0; cc < NCH; ++cc) {
        if (cc < NCH - 1) { asm volatile("s_waitcnt vmcnt(2)" ::: "memory"); }
        else              { asm volatile("s_waitcnt vmcnt(0)" ::: "memory"); }
        __builtin_amdgcn_s_barrier();
        if (cc + 2 < NCH) STAGE_K((cc + 2) % 3, cc + 2);
        __builtin_amdgcn_sched_barrier(0);
        const char* kb = klds + (cc % 3) * 8192;
        #pragma unroll
        for (int nt = 0; nt < 4; ++nt) {
            const int o = (nt * 16 + lrow) * 128 + lgrp * 16;
            bf16x8 a0 = *(const bf16x8*)(kb + swz(o));
            bf16x8 a1 = *(const bf16x8*)(kb + swz(o + 64));
            f32x4 acc = (f32x4){0.f, 0.f, 0.f, 0.f};
            acc = __builtin_amdgcn_mfma_f32_16x16x32_bf16(a0, qf0, acc, 0, 0, 0);
            acc = __builtin_amdgcn_mfma_f32_16x16x32_bf16(a1, qf1, acc, 0, 0, 0);
            rpa0 += __builtin_amdgcn_exp2f(acc[0]);
            rpa1 += __builtin_amdgcn_exp2f(acc[1]);
            rpa2 += __builtin_amdgcn_exp2f(acc[2]);
            rpa3 += __builtin_amdgcn_exp2f(acc[3]);
        }
    }
    float rp = (rpa0 + rpa1) + (rpa2 + rpa3);
    rp += __shfl_xor(rp, 16, 64);
    rp += __shfl_xor(rp, 32, 64);
    const float inv = 1.0f / rp;

    // inter-pass barrier
    __builtin_amdgcn_sched_barrier(0);
    __builtin_amdgcn_s_barrier();

    // ================= pass B: attn + PV =================
    f32x4 o4[4];
    #pragma unroll
    for (int nd = 0; nd < 4; ++nd) o4[nd] = (f32x4){0.f, 0.f, 0.f, 0.f};

    float* abase = attn + (size_t)bh * T_SEQ * T_SEQ;

    // prologue: K stages then V(0); force gll(0) done (allow gll(1)+V(0)=10)
    STAGE_K(0, 0);
    STAGE_K(1, 1);
    bf16x8 vf[8];
    #pragma unroll
    for (int nd = 0; nd < 4; ++nd)
        #pragma unroll
        for (int ks = 0; ks < 2; ++ks)
            vf[nd * 2 + ks] = *(const bf16x8*)(vgb + (size_t)(nd * 16 + lrow) * T_SEQ
                                               + ks * 32 + lgrp * 8);
    asm volatile("s_waitcnt vmcnt(10)" ::: "memory");

    for (int cc = 0; cc < NCH; ++cc) {
        __builtin_amdgcn_s_barrier();
        __builtin_amdgcn_sched_barrier(0);

        // QK^T from staged K: lane -> S[q=lrow][s = nt*16 + lgrp*4 + j]
        const char* kb = klds + (cc % 3) * 8192;
        f32x4 s4[4];
        #pragma unroll
        for (int nt = 0; nt < 4; ++nt) {
            const int o = (nt * 16 + lrow) * 128 + lgrp * 16;
            bf16x8 a0 = *(const bf16x8*)(kb + swz(o));
            bf16x8 a1 = *(const bf16x8*)(kb + swz(o + 64));
            f32x4 acc = (f32x4){0.f, 0.f, 0.f, 0.f};
            acc = __builtin_amdgcn_mfma_f32_16x16x32_bf16(a0, qf0, acc, 0, 0, 0);
            acc = __builtin_amdgcn_mfma_f32_16x16x32_bf16(a1, qf1, acc, 0, 0, 0);
            s4[nt] = acc;
        }
        // normalized P via exp2 (Q pre-scaled by 0.125/ln2)
        #pragma unroll
        for (int nt = 0; nt < 4; ++nt) {
            s4[nt][0] = __builtin_amdgcn_exp2f(s4[nt][0]) * inv;
            s4[nt][1] = __builtin_amdgcn_exp2f(s4[nt][1]) * inv;
            s4[nt][2] = __builtin_amdgcn_exp2f(s4[nt][2]) * inv;
            s4[nt][3] = __builtin_amdgcn_exp2f(s4[nt][3]) * inv;
        }
        // P f32 -> tbuf (swizzled); serves PV A-frags AND store transpose
        #pragma unroll
        for (int nt = 0; nt < 4; ++nt)
            *(f32x4*)(tlds + tswz(lrow, (nt * 16 + lgrp * 4) * 4)) = s4[nt];
        asm volatile("s_waitcnt lgkmcnt(0)" ::: "memory");
        __builtin_amdgcn_sched_barrier(0);

        // PV A-frags: read 8 f32 per ks from tbuf, cvt to bf16x8
        #pragma unroll
        for (int ks = 0; ks < 2; ++ks) {
            f32x4 pa0 = *(const f32x4*)(tlds + tswz(lrow, (ks * 32 + lgrp * 8) * 4));
            f32x4 pa1 = *(const f32x4*)(tlds + tswz(lrow, (ks * 32 + lgrp * 8 + 4) * 4));
            bf16x8 pa;
            pa[0] = (short)f2bf(pa0[0]); pa[1] = (short)f2bf(pa0[1]);
            pa[2] = (short)f2bf(pa0[2]); pa[3] = (short)f2bf(pa0[3]);
            pa[4] = (short)f2bf(pa1[0]); pa[5] = (short)f2bf(pa1[1]);
            pa[6] = (short)f2bf(pa1[2]); pa[7] = (short)f2bf(pa1[3]);
            #pragma unroll
            for (int nd = 0; nd < 4; ++nd)
                o4[nd] = __builtin_amdgcn_mfma_f32_16x16x32_bf16(pa, vf[nd * 2 + ks], o4[nd], 0, 0, 0);
        }
        // transpose read-back: inst i covers rows 4i..4i+3, 256B contiguous/row
        f32x4 tr[4];
        #pragma unroll
        for (int i = 0; i < 4; ++i)
            tr[i] = *(const f32x4*)(tlds + tswz(i * 4 + (lane >> 4), (lane & 15) * 16));
        __builtin_amdgcn_sched_barrier(0);
        // V loads for cc+1 (WAR-safe), then K stage, then stores (youngest)
        if (cc + 1 < NCH) {
            #pragma unroll
            for (int nd = 0; nd < 4; ++nd)
                #pragma unroll
                for (int ks = 0; ks < 2; ++ks)
                    vf[nd * 2 + ks] = *(const bf16x8*)(vgb + (size_t)(nd * 16 + lrow) * T_SEQ
                                                       + (cc + 1) * 64 + ks * 32 + lgrp * 8);
        }
        if (cc + 2 < NCH) STAGE_K((cc + 2) % 3, cc + 2);
        __builtin_amdgcn_sched_barrier(0);
        // attn stores: 4 insts, each 4 rows x 256B contiguous
        #pragma unroll
        for (int i = 0; i < 4; ++i)
            __builtin_nontemporal_store(tr[i],
                (f32x4*)(abase + (size_t)(t0 + i * 4 + (lane >> 4)) * T_SEQ
                         + cc * 64 + (lane & 15) * 4));
        __builtin_amdgcn_sched_barrier(0);
        // tail: force gll(cc+1); allow [stores(cc)4 + STAGE(cc+2)2 + V(cc+1)8
        // + stores(cc-1)4] = 18 youngest in flight
        if (cc < NCH - 2)      { asm volatile("s_waitcnt vmcnt(18)" ::: "memory"); }
        else if (cc < NCH - 1) { asm volatile("s_waitcnt vmcnt(16)" ::: "memory"); }
    }

    // out store: lane holds out[t0 + lgrp*4 + j][nd*16 + lrow] (normalized)
    #pragma unroll
    for (int nd = 0; nd < 4; ++nd)
        #pragma unroll
        for (int j = 0; j < 4; ++j)
            __builtin_nontemporal_store(o4[nd][j],
                out + base + (size_t)(t0 + lgrp * 4 + j) * D_HEAD + nd * 16 + lrow);

#undef STAGE_K
}

extern "C" void kernel_launch(void* const* d_in, const int* in_sizes, int n_in,
                              void* d_out, int out_size, void* d_ws, size_t ws_size,
                              hipStream_t stream) {
    const float* q = (const float*)d_in[0];
    const float* k = (const float*)d_in[1];
    const float* v = (const float*)d_in[2];
    float* out  = (float*)d_out;
    float* attn = out + (size_t)OUT_ELEMS;

    float* ctab = (float*)d_ws;                              // T*32 f32
    float* stab = ctab + T_SEQ * 32;                         // T*32 f32
    unsigned short* wsu = (unsigned short*)(stab + T_SEQ * 32);
    const size_t NE = (size_t)BH_N * T_SEQ * D_HEAD;         // 4,194,304
    unsigned short* Qb = wsu + 0 * NE;
    unsigned short* Kb = wsu + 1 * NE;
    unsigned short* Vt = wsu + 2 * NE;                       // ~25.7 MB total

    const float QSCALE = 0.18033688011112042f;               // 0.125 / ln(2)

    rope_table_kernel<<<dim3((T_SEQ * 32 + 255) / 256), dim3(256), 0, stream>>>(ctab, stab);
    ropebf16_kernel<<<dim3(BH_N * T_SEQ / 16, 2), dim3(256), 0, stream>>>(q, k, ctab, stab, Qb, Kb, QSCALE);
    vtbf16_kernel<<<dim3(T_SEQ / 64, BH_N), dim3(256), 0, stream>>>(v, Vt);
    attn_mfma_kernel<<<dim3(BH_N * T_SEQ / 64), dim3(256), 0, stream>>>(Qb, Kb, Vt, out, attn);
}